// Round 5
// baseline (805.087 us; speedup 1.0000x reference)
//
#include <hip/hip_runtime.h>
#include <hip/hip_bf16.h>

#define FDIM 128

typedef __attribute__((ext_vector_type(8))) short bf16x8;
typedef __attribute__((ext_vector_type(4))) float f32x4;

__device__ __forceinline__ float sp(float x) {
    // softplus = log(1+exp(x)), numerically stable (== jnp.logaddexp(x,0))
    return fmaxf(x, 0.0f) + log1pf(expf(-fabsf(x)));
}

__device__ __forceinline__ unsigned short bfb(float x) {
    // f32 -> bf16 round-to-nearest-even (inputs are finite)
    unsigned int u = __float_as_uint(x);
    u += 0x7FFFu + ((u >> 16) & 1u);
    return (unsigned short)(u >> 16);
}

// Stage W^T into LDS as XOR-swizzled bf16 Wt[n][k]. 256 threads.
__device__ __forceinline__ void stage_w(short* Wt, const float* __restrict__ W, int t) {
#pragma unroll
    for (int i = 0; i < 8; ++i) {
        int e  = t + 256 * i;
        int k  = (e >> 5) * 2;
        int n4 = (e & 31) * 4;
        float4 a = *(const float4*)(W + (size_t)k * FDIM + n4);
        float4 b = *(const float4*)(W + (size_t)(k + 1) * FDIM + n4);
        float av[4] = {a.x, a.y, a.z, a.w};
        float bv[4] = {b.x, b.y, b.z, b.w};
#pragma unroll
        for (int j = 0; j < 4; ++j) {
            int n = n4 + j;
            unsigned int pk = (unsigned int)bfb(av[j]) | ((unsigned int)bfb(bv[j]) << 16);
            int byte = n * 256 + k * 2;
            byte ^= (n & 7) << 4;              // bank-conflict swizzle
            *(unsigned int*)((char*)Wt + byte) = pk;
        }
    }
}

// 32 MFMA: full K=128, 8 n-tiles. afr/acc register arrays (unrolled, const-indexed).
__device__ __forceinline__ void mfma_128(const short* Wt, const bf16x8* afr,
                                         int lane, f32x4* acc) {
#pragma unroll
    for (int ks = 0; ks < 4; ++ks)
#pragma unroll
        for (int n = 0; n < 8; ++n) {
            int nn = n * 16 + (lane & 15);
            int byte = nn * 256 + (ks * 32 + (lane >> 4) * 8) * 2;
            byte ^= (nn & 7) << 4;
            bf16x8 bfr = *(const bf16x8*)((const char*)Wt + byte);
            acc[n] = __builtin_amdgcn_mfma_f32_16x16x32_bf16(afr[ks], bfr, acc[n], 0, 0, 0);
        }
}

// ---------------------------------------------------------------------------
// fused_embed: xi = act(act(emb@Wi+bi)), xj = act(act(emb@Wj+bj)) in one pass.
__global__ __launch_bounds__(256) void fused_embed(
    const float* __restrict__ emb, const float* __restrict__ Wi,
    const float* __restrict__ bi, const float* __restrict__ Wj,
    const float* __restrict__ bj, float* __restrict__ xi,
    float* __restrict__ xj, int nrows)
{
    __shared__ short Wt[FDIM * FDIM];   // 32 KB
    const int t = threadIdx.x, lane = t & 63, wave = t >> 6;
    const int cl = lane & 15, rg = lane >> 4;
    const int rowA = blockIdx.x * 64 + wave * 16 + cl;
    const int kc   = rg * 8;
    const int rb   = blockIdx.x * 64 + wave * 16 + rg * 4;
    const bool rowok = rowA < nrows;

    bf16x8 afr[4];
#pragma unroll
    for (int ks = 0; ks < 4; ++ks) {
        float4 a = make_float4(0.f,0.f,0.f,0.f), b = make_float4(0.f,0.f,0.f,0.f);
        if (rowok) {
            const float* xp = emb + (size_t)rowA * FDIM + ks * 32 + kc;
            a = *(const float4*)xp; b = *(const float4*)(xp + 4);
        }
        bf16x8 f;
        f[0]=(short)bfb(a.x); f[1]=(short)bfb(a.y); f[2]=(short)bfb(a.z); f[3]=(short)bfb(a.w);
        f[4]=(short)bfb(b.x); f[5]=(short)bfb(b.y); f[6]=(short)bfb(b.z); f[7]=(short)bfb(b.w);
        afr[ks] = f;
    }

    stage_w(Wt, Wi, t);
    __syncthreads();
    f32x4 acc[8];
#pragma unroll
    for (int n = 0; n < 8; ++n) acc[n] = (f32x4){0.f,0.f,0.f,0.f};
    mfma_128(Wt, afr, lane, acc);
#pragma unroll
    for (int n = 0; n < 8; ++n) {
        int col = n * 16 + cl; float bc = bi[col];
#pragma unroll
        for (int i = 0; i < 4; ++i) {
            int gr = rb + i;
            if (gr < nrows) xi[(size_t)gr * FDIM + col] = sp(sp(acc[n][i] + bc));
        }
    }
    __syncthreads();                    // Wt reads done before restage
    stage_w(Wt, Wj, t);
    __syncthreads();
#pragma unroll
    for (int n = 0; n < 8; ++n) acc[n] = (f32x4){0.f,0.f,0.f,0.f};
    mfma_128(Wt, afr, lane, acc);
#pragma unroll
    for (int n = 0; n < 8; ++n) {
        int col = n * 16 + cl; float bc = bj[col];
#pragma unroll
        for (int i = 0; i < 4; ++i) {
            int gr = rb + i;
            if (gr < nrows) xj[(size_t)gr * FDIM + col] = sp(sp(acc[n][i] + bc));
        }
    }
}

// ---------------------------------------------------------------------------
// fused_res: nstages residual blocks in-place on X, x kept in C-frag registers.
// per stage: x += act(act(x)@W1+b1)@W2 + b2
__global__ __launch_bounds__(256) void fused_res(
    const float* __restrict__ W1a, const float* __restrict__ B1a,
    const float* __restrict__ W2a, const float* __restrict__ B2a,
    float* __restrict__ X, int nrows, int nstages)
{
    __shared__ short Wt[FDIM * FDIM];   // 32 KB
    __shared__ short XH[64 * FDIM];     // 16 KB swizzled bf16 scratch
    const int t = threadIdx.x, lane = t & 63, wave = t >> 6;
    const int cl = lane & 15, rg = lane >> 4;
    const int kc = rg * 8;
    const int lrowA = wave * 16 + cl;       // local A-frag row
    const int lrb   = wave * 16 + rg * 4;   // local C-frag row base
    const int rb    = blockIdx.x * 64 + lrb;

    // load x in C-frag layout
    float xr[8][4];
#pragma unroll
    for (int n = 0; n < 8; ++n)
#pragma unroll
        for (int i = 0; i < 4; ++i) {
            int gr = rb + i;
            xr[n][i] = (gr < nrows) ? X[(size_t)gr * FDIM + n * 16 + cl] : 0.f;
        }

    for (int s = 0; s < nstages; ++s) {
        const float* w1 = W1a + (size_t)s * FDIM * FDIM;
        const float* b1 = B1a + (size_t)s * FDIM;
        const float* w2 = W2a + (size_t)s * FDIM * FDIM;
        const float* b2 = B2a + (size_t)s * FDIM;

        // 1. act(x) -> XH   (prev stage's Wt/XH reads are all before this point)
#pragma unroll
        for (int n = 0; n < 8; ++n)
#pragma unroll
            for (int i = 0; i < 4; ++i) {
                int lr = lrb + i, col = n * 16 + cl;
                int byte = (lr * 256 + col * 2) ^ ((lr & 7) << 4);
                *(short*)((char*)XH + byte) = (short)bfb(sp(xr[n][i]));
            }
        __syncthreads();

        // 2. afr <- XH ; stage W1
        bf16x8 afr[4];
#pragma unroll
        for (int ks = 0; ks < 4; ++ks) {
            int byte = (lrowA * 256 + (ks * 32 + kc) * 2) ^ ((lrowA & 7) << 4);
            afr[ks] = *(const bf16x8*)((const char*)XH + byte);
        }
        stage_w(Wt, w1, t);
        __syncthreads();

        // 3. H = act(mfma + b1)
        f32x4 hacc[8];
#pragma unroll
        for (int n = 0; n < 8; ++n) hacc[n] = (f32x4){0.f,0.f,0.f,0.f};
        mfma_128(Wt, afr, lane, hacc);
        float hval[8][4];
#pragma unroll
        for (int n = 0; n < 8; ++n) {
            float bc = b1[n * 16 + cl];
#pragma unroll
            for (int i = 0; i < 4; ++i) hval[n][i] = sp(hacc[n][i] + bc);
        }
        __syncthreads();    // all XH/Wt reads done before overwrite

        // 4. H -> XH
#pragma unroll
        for (int n = 0; n < 8; ++n)
#pragma unroll
            for (int i = 0; i < 4; ++i) {
                int lr = lrb + i, col = n * 16 + cl;
                int byte = (lr * 256 + col * 2) ^ ((lr & 7) << 4);
                *(short*)((char*)XH + byte) = (short)bfb(hval[n][i]);
            }
        __syncthreads();

        // 5. afr <- XH(H) ; stage W2
#pragma unroll
        for (int ks = 0; ks < 4; ++ks) {
            int byte = (lrowA * 256 + (ks * 32 + kc) * 2) ^ ((lrowA & 7) << 4);
            afr[ks] = *(const bf16x8*)((const char*)XH + byte);
        }
        stage_w(Wt, w2, t);
        __syncthreads();

        // 6. x += mfma + b2
        f32x4 acc2[8];
#pragma unroll
        for (int n = 0; n < 8; ++n) acc2[n] = (f32x4){0.f,0.f,0.f,0.f};
        mfma_128(Wt, afr, lane, acc2);
#pragma unroll
        for (int n = 0; n < 8; ++n) {
            float bc = b2[n * 16 + cl];
#pragma unroll
            for (int i = 0; i < 4; ++i) xr[n][i] += acc2[n][i] + bc;
        }
        __syncthreads();    // Wt/XH consumed; safe for next stage's writes
    }

    // store x
#pragma unroll
    for (int n = 0; n < 8; ++n)
#pragma unroll
        for (int i = 0; i < 4; ++i) {
            int gr = rb + i;
            if (gr < nrows) X[(size_t)gr * FDIM + n * 16 + cl] = xr[n][i];
        }
}

// ---------------------------------------------------------------------------
// fused_tail: updated = gate*emb + act(xi)@Wv + bv  (written to d_out)
//             y = residual(updated, ow1..ob2); pred = y@Wout + bout
__global__ __launch_bounds__(256) void fused_tail(
    const float* __restrict__ xi, const float* __restrict__ emb,
    const float* __restrict__ Wv, const float* __restrict__ bv,
    const float* __restrict__ gate,
    const float* __restrict__ ow1, const float* __restrict__ ob1,
    const float* __restrict__ ow2, const float* __restrict__ ob2,
    const float* __restrict__ Wout, const float* __restrict__ bout,
    float* __restrict__ updated, float* __restrict__ pred, int nrows)
{
    __shared__ short Wt[FDIM * FDIM];
    __shared__ short XH[64 * FDIM];
    const int t = threadIdx.x, lane = t & 63, wave = t >> 6;
    const int cl = lane & 15, rg = lane >> 4;
    const int kc = rg * 8;
    const int rowA  = blockIdx.x * 64 + wave * 16 + cl;
    const int lrowA = wave * 16 + cl;
    const int lrb   = wave * 16 + rg * 4;
    const int rb    = blockIdx.x * 64 + lrb;
    const bool rowok = rowA < nrows;

    // A-frags = act(xi) straight from global
    bf16x8 afr[4];
#pragma unroll
    for (int ks = 0; ks < 4; ++ks) {
        float4 a = make_float4(0.f,0.f,0.f,0.f), b = make_float4(0.f,0.f,0.f,0.f);
        if (rowok) {
            const float* xp = xi + (size_t)rowA * FDIM + ks * 32 + kc;
            a = *(const float4*)xp; b = *(const float4*)(xp + 4);
        }
        a.x=sp(a.x); a.y=sp(a.y); a.z=sp(a.z); a.w=sp(a.w);
        b.x=sp(b.x); b.y=sp(b.y); b.z=sp(b.z); b.w=sp(b.w);
        bf16x8 f;
        f[0]=(short)bfb(a.x); f[1]=(short)bfb(a.y); f[2]=(short)bfb(a.z); f[3]=(short)bfb(a.w);
        f[4]=(short)bfb(b.x); f[5]=(short)bfb(b.y); f[6]=(short)bfb(b.z); f[7]=(short)bfb(b.w);
        afr[ks] = f;
    }

    stage_w(Wt, Wv, t);
    __syncthreads();
    f32x4 acc[8];
#pragma unroll
    for (int n = 0; n < 8; ++n) acc[n] = (f32x4){0.f,0.f,0.f,0.f};
    mfma_128(Wt, afr, lane, acc);

    // u = gate*emb + acc + bv ; write updated
    float ur[8][4];
#pragma unroll
    for (int n = 0; n < 8; ++n) {
        int col = n * 16 + cl;
        float bc = bv[col], gc = gate[col];
#pragma unroll
        for (int i = 0; i < 4; ++i) {
            int gr = rb + i;
            float ev = (gr < nrows) ? emb[(size_t)gr * FDIM + col] : 0.f;
            ur[n][i] = fmaf(gc, ev, acc[n][i] + bc);
            if (gr < nrows) updated[(size_t)gr * FDIM + col] = ur[n][i];
        }
    }

    // ores residual block on u
#pragma unroll
    for (int n = 0; n < 8; ++n)
#pragma unroll
        for (int i = 0; i < 4; ++i) {
            int lr = lrb + i, col = n * 16 + cl;
            int byte = (lr * 256 + col * 2) ^ ((lr & 7) << 4);
            *(short*)((char*)XH + byte) = (short)bfb(sp(ur[n][i]));
        }
    __syncthreads();                    // XH ready; Wv reads done
#pragma unroll
    for (int ks = 0; ks < 4; ++ks) {
        int byte = (lrowA * 256 + (ks * 32 + kc) * 2) ^ ((lrowA & 7) << 4);
        afr[ks] = *(const bf16x8*)((const char*)XH + byte);
    }
    stage_w(Wt, ow1, t);
    __syncthreads();
    f32x4 hacc[8];
#pragma unroll
    for (int n = 0; n < 8; ++n) hacc[n] = (f32x4){0.f,0.f,0.f,0.f};
    mfma_128(Wt, afr, lane, hacc);
    float hval[8][4];
#pragma unroll
    for (int n = 0; n < 8; ++n) {
        float bc = ob1[n * 16 + cl];
#pragma unroll
        for (int i = 0; i < 4; ++i) hval[n][i] = sp(hacc[n][i] + bc);
    }
    __syncthreads();
#pragma unroll
    for (int n = 0; n < 8; ++n)
#pragma unroll
        for (int i = 0; i < 4; ++i) {
            int lr = lrb + i, col = n * 16 + cl;
            int byte = (lr * 256 + col * 2) ^ ((lr & 7) << 4);
            *(short*)((char*)XH + byte) = (short)bfb(hval[n][i]);
        }
    __syncthreads();
#pragma unroll
    for (int ks = 0; ks < 4; ++ks) {
        int byte = (lrowA * 256 + (ks * 32 + kc) * 2) ^ ((lrowA & 7) << 4);
        afr[ks] = *(const bf16x8*)((const char*)XH + byte);
    }
    stage_w(Wt, ow2, t);
    __syncthreads();
    f32x4 acc2[8];
#pragma unroll
    for (int n = 0; n < 8; ++n) acc2[n] = (f32x4){0.f,0.f,0.f,0.f};
    mfma_128(Wt, afr, lane, acc2);

    // y = u + acc2 + ob2 ; fused out_proj
    float p0[4] = {0.f,0.f,0.f,0.f}, p1[4] = {0.f,0.f,0.f,0.f};
#pragma unroll
    for (int n = 0; n < 8; ++n) {
        int col = n * 16 + cl;
        float bc = ob2[col];
        float2 w = *(const float2*)(Wout + col * 2);
#pragma unroll
        for (int i = 0; i < 4; ++i) {
            float y = ur[n][i] + acc2[n][i] + bc;
            p0[i] = fmaf(y, w.x, p0[i]);
            p1[i] = fmaf(y, w.y, p1[i]);
        }
    }
#pragma unroll
    for (int m = 1; m < 16; m <<= 1)
#pragma unroll
        for (int i = 0; i < 4; ++i) {
            p0[i] += __shfl_xor(p0[i], m, 64);
            p1[i] += __shfl_xor(p1[i], m, 64);
        }
    if (cl == 0) {
        float b0 = bout[0], b1v = bout[1];
#pragma unroll
        for (int i = 0; i < 4; ++i) {
            int gr = rb + i;
            if (gr < nrows) {
                pred[(size_t)gr * 2 + 0] = p0[i] + b0;
                pred[(size_t)gr * 2 + 1] = p1[i] + b1v;
            }
        }
    }
}

// ---- CSR build ------------------------------------------------------------

__global__ __launch_bounds__(256) void hist_counts(
    const int* __restrict__ idx_i, int* __restrict__ counts, int npairs)
{
    int p = blockIdx.x * 256 + threadIdx.x;
    if (p < npairs) atomicAdd(&counts[idx_i[p]], 1);
}

__global__ __launch_bounds__(256) void block_sums(
    const int* __restrict__ counts, int* __restrict__ bsum, int n)
{
    __shared__ int s[256];
    const int t = threadIdx.x;
    const int base = blockIdx.x * 2048;
    int sum = 0;
#pragma unroll
    for (int i = 0; i < 8; ++i) {
        int idx = base + t + 256 * i;
        sum += (idx < n) ? counts[idx] : 0;
    }
    s[t] = sum;
    __syncthreads();
    for (int o = 128; o > 0; o >>= 1) {
        if (t < o) s[t] += s[t + o];
        __syncthreads();
    }
    if (t == 0) bsum[blockIdx.x] = s[0];
}

// scan within 2048-elem tiles; inline exclusive-scan of bsum (nb <= 32)
__global__ __launch_bounds__(256) void scan_within(
    const int* __restrict__ counts, const int* __restrict__ bsum,
    int* __restrict__ offsets, int* __restrict__ cursor, int n, int npairs)
{
    __shared__ int ld[2048];
    __shared__ int ps[256];
    __shared__ int tile_base;
    const int t = threadIdx.x;
    const int base = blockIdx.x * 2048;
    if (t == 0) {
        int s = 0;
        for (int i = 0; i < blockIdx.x; ++i) s += bsum[i];
        tile_base = s;
    }
#pragma unroll
    for (int i = 0; i < 8; ++i) {
        int idx = base + t + 256 * i;
        ld[t + 256 * i] = (idx < n) ? counts[idx] : 0;
    }
    __syncthreads();
    int loc[8]; int s = 0;
#pragma unroll
    for (int i = 0; i < 8; ++i) { loc[i] = s; s += ld[t * 8 + i]; }
    ps[t] = s;
    __syncthreads();
    for (int o = 1; o < 256; o <<= 1) {
        int add = (t >= o) ? ps[t - o] : 0;
        __syncthreads();
        ps[t] += add;
        __syncthreads();
    }
    int tbase = tile_base + ((t == 0) ? 0 : ps[t - 1]);
#pragma unroll
    for (int i = 0; i < 8; ++i) {
        int idx = base + t * 8 + i;
        if (idx < n) { int v = tbase + loc[i]; offsets[idx] = v; cursor[idx] = v; }
    }
    if (blockIdx.x == gridDim.x - 1 && t == 255) offsets[n] = npairs;
}

__global__ __launch_bounds__(256) void fill_buckets(
    const int* __restrict__ idx_i, const int* __restrict__ idx_j,
    int* __restrict__ cursor, int* __restrict__ bucket,
    int* __restrict__ jperm, int npairs)
{
    int p = blockIdx.x * 256 + threadIdx.x;
    if (p >= npairs) return;
    int pos = atomicAdd(&cursor[idx_i[p]], 1);
    bucket[pos] = p;
    jperm[pos]  = idx_j[p];
}

// One WAVE per atom, breadth-first batches of 16 pairs.
__global__ __launch_bounds__(256) void pair_gather_wave(
    const float* __restrict__ f_ij, const int* __restrict__ bucket,
    const int* __restrict__ jperm, const int* __restrict__ offsets,
    const float* __restrict__ Wg, const float* __restrict__ xj,
    float* __restrict__ xi, int natoms)
{
    const int lane = threadIdx.x & 63;
    const int wave = threadIdx.x >> 6;
    const int atom = blockIdx.x * 4 + wave;
    if (atom >= natoms) return;

    float2 wreg[16];
#pragma unroll
    for (int r = 0; r < 16; ++r)
        wreg[r] = *(const float2*)(Wg + r * FDIM + lane * 2);

    const int beg = offsets[atom], end = offsets[atom + 1];
    float a0 = 0.f, a1 = 0.f;

    for (int base = beg; base < end; base += 16) {
        int cnt = end - base; if (cnt > 16) cnt = 16;

        int pv = 0, jv = 0;
        if (lane < cnt) {
            pv = bucket[base + lane];
            jv = jperm[base + lane];
        }

        int tq = lane >> 2;
        int pt = __shfl(pv, tq);
        float4 fv = make_float4(0.f, 0.f, 0.f, 0.f);
        if (tq < cnt)
            fv = *(const float4*)(f_ij + (size_t)pt * 16 + (lane & 3) * 4);

        float2 xv[16];
#pragma unroll
        for (int t = 0; t < 16; ++t) {
            xv[t] = make_float2(0.f, 0.f);
            if (t < cnt) {
                int jt = __builtin_amdgcn_readlane(jv, t);
                xv[t] = *(const float2*)(xj + (size_t)jt * FDIM + lane * 2);
            }
        }

#pragma unroll
        for (int t = 0; t < 16; ++t) {
            if (t < cnt) {
                float fr[16];
#pragma unroll
                for (int c = 0; c < 4; ++c) {
                    fr[4*c+0] = __uint_as_float(__builtin_amdgcn_readlane(__float_as_uint(fv.x), 4*t+c));
                    fr[4*c+1] = __uint_as_float(__builtin_amdgcn_readlane(__float_as_uint(fv.y), 4*t+c));
                    fr[4*c+2] = __uint_as_float(__builtin_amdgcn_readlane(__float_as_uint(fv.z), 4*t+c));
                    fr[4*c+3] = __uint_as_float(__builtin_amdgcn_readlane(__float_as_uint(fv.w), 4*t+c));
                }
                float gx = 0.f, gy = 0.f;
#pragma unroll
                for (int r = 0; r < 16; ++r) {
                    gx = fmaf(fr[r], wreg[r].x, gx);
                    gy = fmaf(fr[r], wreg[r].y, gy);
                }
                a0 = fmaf(gx, xv[t].x, a0);
                a1 = fmaf(gy, xv[t].y, a1);
            }
        }
    }

    float2* dst = (float2*)(xi + (size_t)atom * FDIM + lane * 2);
    float2 c = *dst;
    c.x += a0; c.y += a1;
    *dst = c;
}

extern "C" void kernel_launch(void* const* d_in, const int* in_sizes, int n_in,
                              void* d_out, int out_size, void* d_ws, size_t ws_size,
                              hipStream_t stream)
{
    const float* emb     = (const float*)d_in[0];
    const float* f_ij    = (const float*)d_in[1];
    const int*   idx_i   = (const int*)d_in[2];
    const int*   idx_j   = (const int*)d_in[3];
    const float* Wi      = (const float*)d_in[4];
    const float* bi      = (const float*)d_in[5];
    const float* Wj      = (const float*)d_in[6];
    const float* bj      = (const float*)d_in[7];
    const float* Wg      = (const float*)d_in[8];
    const float* Wv      = (const float*)d_in[9];
    const float* bv      = (const float*)d_in[10];
    const float* gate    = (const float*)d_in[11];
    const float* res_w1  = (const float*)d_in[12];
    const float* res_b1  = (const float*)d_in[13];
    const float* res_w2  = (const float*)d_in[14];
    const float* res_b2  = (const float*)d_in[15];
    const float* ores_w1 = (const float*)d_in[16];
    const float* ores_b1 = (const float*)d_in[17];
    const float* ores_w2 = (const float*)d_in[18];
    const float* ores_b2 = (const float*)d_in[19];
    const float* Wout    = (const float*)d_in[20];
    const float* bout    = (const float*)d_in[21];

    const int N = in_sizes[0] / FDIM;   // 50000
    const int P = in_sizes[2];          // 800000

    float* xi      = (float*)d_ws;                      // [N,128]
    float* xj      = xi + (size_t)N * FDIM;             // [N,128]
    int*   counts  = (int*)(xj + (size_t)N * FDIM);     // [N]
    int*   offsets = counts + N;                        // [N+1]
    int*   cursor  = offsets + N + 1;                   // [N]
    int*   bucket  = cursor + N;                        // [P]
    int*   jperm   = bucket + P;                        // [P]
    int*   bsum    = jperm + P;                         // [<=32]
    float* pred    = (float*)d_out;                     // [N,2]
    float* updated = (float*)d_out + (size_t)N * 2;     // [N,128]

    const dim3 blk(256);
    const int ggrid = (N + 63) / 64;
    const int pgrid = (P + 255) / 256;
    const int nb    = (N + 2047) / 2048;

    // CSR build (int atomics only)
    hipMemsetAsync(counts, 0, (size_t)N * sizeof(int), stream);
    hist_counts<<<pgrid, blk, 0, stream>>>(idx_i, counts, P);
    block_sums<<<nb, blk, 0, stream>>>(counts, bsum, N);
    scan_within<<<nb, blk, 0, stream>>>(counts, bsum, offsets, cursor, N, P);
    fill_buckets<<<pgrid, blk, 0, stream>>>(idx_i, idx_j, cursor, bucket, jperm, P);

    // xi = act(act(emb@Wi+bi)); xj = act(act(emb@Wj+bj))
    fused_embed<<<ggrid, blk, 0, stream>>>(emb, Wi, bi, Wj, bj, xi, xj, N);

    // xi[i] += sum over pairs of (f_ij @ Wg) * xj[idx_j]
    pair_gather_wave<<<(N + 3) / 4, blk, 0, stream>>>(f_ij, bucket, jperm, offsets,
                                                      Wg, xj, xi, N);

    // 3 residual blocks in one kernel
    fused_res<<<ggrid, blk, 0, stream>>>(res_w1, res_b1, res_w2, res_b2, xi, N, 3);

    // updated + ores residual + prediction in one kernel
    fused_tail<<<ggrid, blk, 0, stream>>>(xi, emb, Wv, bv, gate,
                                          ores_w1, ores_b1, ores_w2, ores_b2,
                                          Wout, bout, updated, pred, N);
}

// Round 6
// 324.922 us; speedup vs baseline: 2.4778x; 2.4778x over previous
//
#include <hip/hip_runtime.h>
#include <hip/hip_bf16.h>

#define FDIM 128

typedef __attribute__((ext_vector_type(8))) short bf16x8;
typedef __attribute__((ext_vector_type(4))) float f32x4;

__device__ __forceinline__ float sp(float x) {
    // softplus = max(x,0) + ln2*log2(1 + 2^(-|x|*log2e)) ; HW v_exp/v_log
    float t = __builtin_amdgcn_exp2f(-fabsf(x) * 1.44269504088896f);
    return fmaxf(x, 0.0f) + 0.69314718055994531f * __builtin_amdgcn_logf(1.0f + t);
}

__device__ __forceinline__ unsigned short bfb(float x) {
    // f32 -> bf16 round-to-nearest-even (inputs finite)
    unsigned int u = __float_as_uint(x);
    u += 0x7FFFu + ((u >> 16) & 1u);
    return (unsigned short)(u >> 16);
}

__device__ __forceinline__ bf16x8 pack8(float4 a, float4 b) {
    bf16x8 f;
    f[0]=(short)bfb(a.x); f[1]=(short)bfb(a.y); f[2]=(short)bfb(a.z); f[3]=(short)bfb(a.w);
    f[4]=(short)bfb(b.x); f[5]=(short)bfb(b.y); f[6]=(short)bfb(b.z); f[7]=(short)bfb(b.w);
    return f;
}

// copy one pre-converted, pre-swizzled 32KB bf16 weight image into LDS.
// consecutive lanes -> consecutive 16B: conflict-free ds_write_b128.
__device__ __forceinline__ void stage_wt(short* Wt, const short* __restrict__ src, int t) {
    const uint4* s4 = (const uint4*)src;
    uint4* d4 = (uint4*)Wt;
#pragma unroll
    for (int i = 0; i < 8; ++i) d4[t + 256 * i] = s4[t + 256 * i];
}

// 32 MFMA: full K=128, 8 n-tiles against swizzled Wt[n][k].
__device__ __forceinline__ void mfma_128(const short* Wt, const bf16x8* afr,
                                         int lane, f32x4* acc) {
#pragma unroll
    for (int ks = 0; ks < 4; ++ks)
#pragma unroll
        for (int n = 0; n < 8; ++n) {
            int nn = n * 16 + (lane & 15);
            int byte = nn * 256 + (ks * 32 + (lane >> 4) * 8) * 2;
            byte ^= (nn & 7) << 4;
            bf16x8 bfr = *(const bf16x8*)((const char*)Wt + byte);
            acc[n] = __builtin_amdgcn_mfma_f32_16x16x32_bf16(afr[ks], bfr, acc[n], 0, 0, 0);
        }
}

// ---------------------------------------------------------------------------
// wconv: convert 11 [128,128] f32 weights -> transposed/swizzled bf16 images.
struct WP { const float* w[11]; };

__global__ __launch_bounds__(256) void wconv(WP wp, short* __restrict__ dst) {
    const float* W = wp.w[blockIdx.y];
    char* out = (char*)(dst + (size_t)blockIdx.y * 16384);
    int e = blockIdx.x * 256 + threadIdx.x;        // e = kp*128 + n
    int n = e & 127, k = (e >> 7) * 2;
    float a = W[(size_t)k * FDIM + n];
    float b = W[(size_t)(k + 1) * FDIM + n];
    unsigned int pk = (unsigned int)bfb(a) | ((unsigned int)bfb(b) << 16);
    int byte = (n * 256 + k * 2) ^ ((n & 7) << 4);
    *(unsigned int*)(out + byte) = pk;
}

// ---------------------------------------------------------------------------
// fused_embed: xi = act(act(emb@Wi+bi)), xj = act(act(emb@Wj+bj))
__global__ __launch_bounds__(256) void fused_embed(
    const float* __restrict__ emb, const short* __restrict__ wsw,
    const float* __restrict__ bi, const float* __restrict__ bj,
    float* __restrict__ xi, float* __restrict__ xj, int nrows)
{
    __shared__ __align__(16) short Wt[FDIM * FDIM];   // 32 KB
    const int t = threadIdx.x, lane = t & 63, wave = t >> 6;
    const int cl = lane & 15, rg = lane >> 4;
    const int rowA = blockIdx.x * 64 + wave * 16 + cl;
    const int kc   = rg * 8;
    const int rb   = blockIdx.x * 64 + wave * 16 + rg * 4;
    const bool rowok = rowA < nrows;

    bf16x8 afr[4];
#pragma unroll
    for (int ks = 0; ks < 4; ++ks) {
        float4 a = make_float4(0.f,0.f,0.f,0.f), b = make_float4(0.f,0.f,0.f,0.f);
        if (rowok) {
            const float* xp = emb + (size_t)rowA * FDIM + ks * 32 + kc;
            a = *(const float4*)xp; b = *(const float4*)(xp + 4);
        }
        afr[ks] = pack8(a, b);
    }

    stage_wt(Wt, wsw + 0 * 16384, t);    // Wi
    __syncthreads();
    f32x4 acc[8];
#pragma unroll
    for (int n = 0; n < 8; ++n) acc[n] = (f32x4){0.f,0.f,0.f,0.f};
    mfma_128(Wt, afr, lane, acc);
#pragma unroll
    for (int n = 0; n < 8; ++n) {
        int col = n * 16 + cl; float bc = bi[col];
#pragma unroll
        for (int i = 0; i < 4; ++i) {
            int gr = rb + i;
            if (gr < nrows) xi[(size_t)gr * FDIM + col] = sp(sp(acc[n][i] + bc));
        }
    }
    __syncthreads();                     // Wt reads done before restage
    stage_wt(Wt, wsw + 1 * 16384, t);    // Wj
    __syncthreads();
#pragma unroll
    for (int n = 0; n < 8; ++n) acc[n] = (f32x4){0.f,0.f,0.f,0.f};
    mfma_128(Wt, afr, lane, acc);
#pragma unroll
    for (int n = 0; n < 8; ++n) {
        int col = n * 16 + cl; float bc = bj[col];
#pragma unroll
        for (int i = 0; i < 4; ++i) {
            int gr = rb + i;
            if (gr < nrows) xj[(size_t)gr * FDIM + col] = sp(sp(acc[n][i] + bc));
        }
    }
}

// ---------------------------------------------------------------------------
// fused_res: 3 residual blocks in-place, x in C-frag registers.
__global__ __launch_bounds__(256) void fused_res(
    const short* __restrict__ wsw,       // slots 2..4 = W1, 5..7 = W2
    const float* __restrict__ B1a, const float* __restrict__ B2a,
    float* __restrict__ X, int nrows, int nstages)
{
    __shared__ __align__(16) short Wt[FDIM * FDIM];   // 32 KB
    __shared__ __align__(16) short XH[64 * FDIM];     // 16 KB
    const int t = threadIdx.x, lane = t & 63, wave = t >> 6;
    const int cl = lane & 15, rg = lane >> 4;
    const int kc = rg * 8;
    const int lrowA = wave * 16 + cl;
    const int lrb   = wave * 16 + rg * 4;
    const int rb    = blockIdx.x * 64 + lrb;

    float xr[8][4];
#pragma unroll
    for (int n = 0; n < 8; ++n)
#pragma unroll
        for (int i = 0; i < 4; ++i) {
            int gr = rb + i;
            xr[n][i] = (gr < nrows) ? X[(size_t)gr * FDIM + n * 16 + cl] : 0.f;
        }

    for (int s = 0; s < nstages; ++s) {
        const float* b1 = B1a + (size_t)s * FDIM;
        const float* b2 = B2a + (size_t)s * FDIM;

        // act(x) -> XH   (prev iter's XH reads all completed before prev bar#4)
#pragma unroll
        for (int n = 0; n < 8; ++n)
#pragma unroll
            for (int i = 0; i < 4; ++i) {
                int lr = lrb + i, col = n * 16 + cl;
                int byte = (lr * 256 + col * 2) ^ ((lr & 7) << 4);
                *(short*)((char*)XH + byte) = (short)bfb(sp(xr[n][i]));
            }
        __syncthreads();                                   // bar 1

        bf16x8 afr[4];
#pragma unroll
        for (int ks = 0; ks < 4; ++ks) {
            int byte = (lrowA * 256 + (ks * 32 + kc) * 2) ^ ((lrowA & 7) << 4);
            afr[ks] = *(const bf16x8*)((const char*)XH + byte);
        }
        stage_wt(Wt, wsw + (size_t)(2 + s) * 16384, t);    // W1
        __syncthreads();                                   // bar 2

        f32x4 acc[8];
#pragma unroll
        for (int n = 0; n < 8; ++n) acc[n] = (f32x4){0.f,0.f,0.f,0.f};
        mfma_128(Wt, afr, lane, acc);
        // h = act(acc+b1) -> XH (all afr reads done at bar 2)
#pragma unroll
        for (int n = 0; n < 8; ++n) {
            float bc = b1[n * 16 + cl];
#pragma unroll
            for (int i = 0; i < 4; ++i) {
                int lr = lrb + i, col = n * 16 + cl;
                int byte = (lr * 256 + col * 2) ^ ((lr & 7) << 4);
                *(short*)((char*)XH + byte) = (short)bfb(sp(acc[n][i] + bc));
            }
        }
        __syncthreads();                                   // bar 3

#pragma unroll
        for (int ks = 0; ks < 4; ++ks) {
            int byte = (lrowA * 256 + (ks * 32 + kc) * 2) ^ ((lrowA & 7) << 4);
            afr[ks] = *(const bf16x8*)((const char*)XH + byte);
        }
        stage_wt(Wt, wsw + (size_t)(5 + s) * 16384, t);    // W2
        __syncthreads();                                   // bar 4

#pragma unroll
        for (int n = 0; n < 8; ++n) acc[n] = (f32x4){0.f,0.f,0.f,0.f};
        mfma_128(Wt, afr, lane, acc);
#pragma unroll
        for (int n = 0; n < 8; ++n) {
            float bc = b2[n * 16 + cl];
#pragma unroll
            for (int i = 0; i < 4; ++i) xr[n][i] += acc[n][i] + bc;
        }
        __syncthreads();                                   // bar 5 (Wt/XH free)
    }

#pragma unroll
    for (int n = 0; n < 8; ++n)
#pragma unroll
        for (int i = 0; i < 4; ++i) {
            int gr = rb + i;
            if (gr < nrows) X[(size_t)gr * FDIM + n * 16 + cl] = xr[n][i];
        }
}

// ---------------------------------------------------------------------------
// fused_tail: updated = gate*emb + act(xi)@Wv + bv ; ores residual ; out proj
__global__ __launch_bounds__(256) void fused_tail(
    const float* __restrict__ xi, const float* __restrict__ emb,
    const short* __restrict__ wsw,       // slot 8 = Wv, 9 = ow1, 10 = ow2
    const float* __restrict__ bv, const float* __restrict__ gate,
    const float* __restrict__ ob1, const float* __restrict__ ob2,
    const float* __restrict__ Wout, const float* __restrict__ bout,
    float* __restrict__ updated, float* __restrict__ pred, int nrows)
{
    __shared__ __align__(16) short Wt[FDIM * FDIM];
    __shared__ __align__(16) short XH[64 * FDIM];
    const int t = threadIdx.x, lane = t & 63, wave = t >> 6;
    const int cl = lane & 15, rg = lane >> 4;
    const int kc = rg * 8;
    const int rowA  = blockIdx.x * 64 + wave * 16 + cl;
    const int lrowA = wave * 16 + cl;
    const int lrb   = wave * 16 + rg * 4;
    const int rb    = blockIdx.x * 64 + lrb;
    const bool rowok = rowA < nrows;

    bf16x8 afr[4];
#pragma unroll
    for (int ks = 0; ks < 4; ++ks) {
        float4 a = make_float4(0.f,0.f,0.f,0.f), b = make_float4(0.f,0.f,0.f,0.f);
        if (rowok) {
            const float* xp = xi + (size_t)rowA * FDIM + ks * 32 + kc;
            a = *(const float4*)xp; b = *(const float4*)(xp + 4);
        }
        a.x=sp(a.x); a.y=sp(a.y); a.z=sp(a.z); a.w=sp(a.w);
        b.x=sp(b.x); b.y=sp(b.y); b.z=sp(b.z); b.w=sp(b.w);
        afr[ks] = pack8(a, b);
    }

    stage_wt(Wt, wsw + (size_t)8 * 16384, t);     // Wv
    __syncthreads();
    f32x4 acc[8];
#pragma unroll
    for (int n = 0; n < 8; ++n) acc[n] = (f32x4){0.f,0.f,0.f,0.f};
    mfma_128(Wt, afr, lane, acc);

    float ur[8][4];
#pragma unroll
    for (int n = 0; n < 8; ++n) {
        int col = n * 16 + cl;
        float bc = bv[col], gc = gate[col];
#pragma unroll
        for (int i = 0; i < 4; ++i) {
            int gr = rb + i;
            float ev = (gr < nrows) ? emb[(size_t)gr * FDIM + col] : 0.f;
            ur[n][i] = fmaf(gc, ev, acc[n][i] + bc);
            if (gr < nrows) updated[(size_t)gr * FDIM + col] = ur[n][i];
        }
    }

    // act(u) -> XH
#pragma unroll
    for (int n = 0; n < 8; ++n)
#pragma unroll
        for (int i = 0; i < 4; ++i) {
            int lr = lrb + i, col = n * 16 + cl;
            int byte = (lr * 256 + col * 2) ^ ((lr & 7) << 4);
            *(short*)((char*)XH + byte) = (short)bfb(sp(ur[n][i]));
        }
    __syncthreads();
#pragma unroll
    for (int ks = 0; ks < 4; ++ks) {
        int byte = (lrowA * 256 + (ks * 32 + kc) * 2) ^ ((lrowA & 7) << 4);
        afr[ks] = *(const bf16x8*)((const char*)XH + byte);
    }
    stage_wt(Wt, wsw + (size_t)9 * 16384, t);     // ow1
    __syncthreads();
#pragma unroll
    for (int n = 0; n < 8; ++n) acc[n] = (f32x4){0.f,0.f,0.f,0.f};
    mfma_128(Wt, afr, lane, acc);
#pragma unroll
    for (int n = 0; n < 8; ++n) {
        float bc = ob1[n * 16 + cl];
#pragma unroll
        for (int i = 0; i < 4; ++i) {
            int lr = lrb + i, col = n * 16 + cl;
            int byte = (lr * 256 + col * 2) ^ ((lr & 7) << 4);
            *(short*)((char*)XH + byte) = (short)bfb(sp(acc[n][i] + bc));
        }
    }
    __syncthreads();
#pragma unroll
    for (int ks = 0; ks < 4; ++ks) {
        int byte = (lrowA * 256 + (ks * 32 + kc) * 2) ^ ((lrowA & 7) << 4);
        afr[ks] = *(const bf16x8*)((const char*)XH + byte);
    }
    stage_wt(Wt, wsw + (size_t)10 * 16384, t);    // ow2
    __syncthreads();
#pragma unroll
    for (int n = 0; n < 8; ++n) acc[n] = (f32x4){0.f,0.f,0.f,0.f};
    mfma_128(Wt, afr, lane, acc);

    float p0[4] = {0.f,0.f,0.f,0.f}, p1[4] = {0.f,0.f,0.f,0.f};
#pragma unroll
    for (int n = 0; n < 8; ++n) {
        int col = n * 16 + cl;
        float bc = ob2[col];
        float2 w = *(const float2*)(Wout + col * 2);
#pragma unroll
        for (int i = 0; i < 4; ++i) {
            float y = ur[n][i] + acc[n][i] + bc;
            p0[i] = fmaf(y, w.x, p0[i]);
            p1[i] = fmaf(y, w.y, p1[i]);
        }
    }
#pragma unroll
    for (int m = 1; m < 16; m <<= 1)
#pragma unroll
        for (int i = 0; i < 4; ++i) {
            p0[i] += __shfl_xor(p0[i], m, 64);
            p1[i] += __shfl_xor(p1[i], m, 64);
        }
    if (cl == 0) {
        float b0 = bout[0], b1v = bout[1];
#pragma unroll
        for (int i = 0; i < 4; ++i) {
            int gr = rb + i;
            if (gr < nrows) {
                pred[(size_t)gr * 2 + 0] = p0[i] + b0;
                pred[(size_t)gr * 2 + 1] = p1[i] + b1v;
            }
        }
    }
}

// ---- CSR build ------------------------------------------------------------

__global__ __launch_bounds__(256) void hist_counts(
    const int* __restrict__ idx_i, int* __restrict__ counts, int npairs)
{
    int p = blockIdx.x * 256 + threadIdx.x;
    if (p < npairs) atomicAdd(&counts[idx_i[p]], 1);
}

__global__ __launch_bounds__(256) void block_sums(
    const int* __restrict__ counts, int* __restrict__ bsum, int n)
{
    __shared__ int s[256];
    const int t = threadIdx.x;
    const int base = blockIdx.x * 2048;
    int sum = 0;
#pragma unroll
    for (int i = 0; i < 8; ++i) {
        int idx = base + t + 256 * i;
        sum += (idx < n) ? counts[idx] : 0;
    }
    s[t] = sum;
    __syncthreads();
    for (int o = 128; o > 0; o >>= 1) {
        if (t < o) s[t] += s[t + o];
        __syncthreads();
    }
    if (t == 0) bsum[blockIdx.x] = s[0];
}

__global__ __launch_bounds__(256) void scan_within(
    const int* __restrict__ counts, const int* __restrict__ bsum,
    int* __restrict__ offsets, int* __restrict__ cursor, int n, int npairs)
{
    __shared__ int ld[2048];
    __shared__ int ps[256];
    __shared__ int tile_base;
    const int t = threadIdx.x;
    const int base = blockIdx.x * 2048;
    if (t == 0) {
        int s = 0;
        for (int i = 0; i < (int)blockIdx.x; ++i) s += bsum[i];
        tile_base = s;
    }
#pragma unroll
    for (int i = 0; i < 8; ++i) {
        int idx = base + t + 256 * i;
        ld[t + 256 * i] = (idx < n) ? counts[idx] : 0;
    }
    __syncthreads();
    int loc[8]; int s = 0;
#pragma unroll
    for (int i = 0; i < 8; ++i) { loc[i] = s; s += ld[t * 8 + i]; }
    ps[t] = s;
    __syncthreads();
    for (int o = 1; o < 256; o <<= 1) {
        int add = (t >= o) ? ps[t - o] : 0;
        __syncthreads();
        ps[t] += add;
        __syncthreads();
    }
    int tbase = tile_base + ((t == 0) ? 0 : ps[t - 1]);
#pragma unroll
    for (int i = 0; i < 8; ++i) {
        int idx = base + t * 8 + i;
        if (idx < n) { int v = tbase + loc[i]; offsets[idx] = v; cursor[idx] = v; }
    }
    if (blockIdx.x == gridDim.x - 1 && t == 255) offsets[n] = npairs;
}

__global__ __launch_bounds__(256) void fill_buckets(
    const int* __restrict__ idx_i, const int* __restrict__ idx_j,
    int* __restrict__ cursor, int* __restrict__ bucket,
    int* __restrict__ jperm, int npairs)
{
    int p = blockIdx.x * 256 + threadIdx.x;
    if (p >= npairs) return;
    int pos = atomicAdd(&cursor[idx_i[p]], 1);
    bucket[pos] = p;
    jperm[pos]  = idx_j[p];
}

// ---------------------------------------------------------------------------
// pair_gather_mfma: one wave per atom. Per 16-pair batch, g = f@Wg computed by
// 8x mfma_16x16x32 (K zero-padded past 16). C-frag row=pair, col matches the
// per-(pair,col) xj gather exactly, so no cross-lane shuffle of g is needed.
__global__ __launch_bounds__(256) void pair_gather_mfma(
    const float* __restrict__ f_ij, const int* __restrict__ bucket,
    const int* __restrict__ jperm, const int* __restrict__ offsets,
    const float* __restrict__ Wg, const float* __restrict__ xj,
    float* __restrict__ xi, int natoms)
{
    const int lane = threadIdx.x & 63;
    const int wave = threadIdx.x >> 6;
    const int atom = blockIdx.x * 4 + wave;
    if (atom >= natoms) return;
    const int cl = lane & 15;
    const int kg = lane >> 4;

    // Wg B-frags: col = 16n+cl, k = kg*8+e (zero for k>=16)
    bf16x8 wg[8];
#pragma unroll
    for (int n = 0; n < 8; ++n) {
        bf16x8 f = (bf16x8){0,0,0,0,0,0,0,0};
        if (kg < 2) {
#pragma unroll
            for (int e = 0; e < 8; ++e)
                f[e] = (short)bfb(Wg[(size_t)(kg * 8 + e) * FDIM + n * 16 + cl]);
        }
        wg[n] = f;
    }

    const int beg = offsets[atom], end = offsets[atom + 1];
    float acc[8];
#pragma unroll
    for (int n = 0; n < 8; ++n) acc[n] = 0.f;

    for (int base = beg; base < end; base += 16) {
        int cnt = end - base; if (cnt > 16) cnt = 16;

        int pv = 0, jv = 0;
        if (lane < cnt) {
            pv = bucket[base + lane];
            jv = jperm[base + lane];
        }

        // j index of this lane-group's 4 pair slots
        int jr0 = __shfl(jv, (lane >> 4) * 4 + 0, 64);
        int jr1 = __shfl(jv, (lane >> 4) * 4 + 1, 64);
        int jr2 = __shfl(jv, (lane >> 4) * 4 + 2, 64);
        int jr3 = __shfl(jv, (lane >> 4) * 4 + 3, 64);

        // xj gathers: lane covers (pair slot i, col 16n+cl)
        float xvv[8][4];
#pragma unroll
        for (int n = 0; n < 8; ++n) {
            int col = n * 16 + cl;
            xvv[n][0] = xj[(size_t)jr0 * FDIM + col];
            xvv[n][1] = xj[(size_t)jr1 * FDIM + col];
            xvv[n][2] = xj[(size_t)jr2 * FDIM + col];
            xvv[n][3] = xj[(size_t)jr3 * FDIM + col];
        }

        // f A-frag: row = pair (lane&15), k = kg*8+e (zero for k>=16 / invalid)
        int prow = __shfl(pv, cl, 64);
        bf16x8 fv = (bf16x8){0,0,0,0,0,0,0,0};
        if (kg < 2 && cl < cnt) {
            const float* fp = f_ij + (size_t)prow * 16 + kg * 8;
            float4 fa = *(const float4*)fp;
            float4 fb = *(const float4*)(fp + 4);
            fv = pack8(fa, fb);
        }

#pragma unroll
        for (int n = 0; n < 8; ++n) {
            f32x4 c = (f32x4){0.f, 0.f, 0.f, 0.f};
            c = __builtin_amdgcn_mfma_f32_16x16x32_bf16(fv, wg[n], c, 0, 0, 0);
            acc[n] = fmaf(c[0], xvv[n][0], acc[n]);
            acc[n] = fmaf(c[1], xvv[n][1], acc[n]);
            acc[n] = fmaf(c[2], xvv[n][2], acc[n]);
            acc[n] = fmaf(c[3], xvv[n][3], acc[n]);
        }
    }

    // reduce over the 4 lane-groups (pair slots), then RMW xi from lanes 0..15
#pragma unroll
    for (int n = 0; n < 8; ++n) {
        acc[n] += __shfl_xor(acc[n], 16, 64);
        acc[n] += __shfl_xor(acc[n], 32, 64);
    }
    if (lane < 16) {
#pragma unroll
        for (int n = 0; n < 8; ++n) {
            float* dst = xi + (size_t)atom * FDIM + n * 16 + lane;
            *dst += acc[n];
        }
    }
}

extern "C" void kernel_launch(void* const* d_in, const int* in_sizes, int n_in,
                              void* d_out, int out_size, void* d_ws, size_t ws_size,
                              hipStream_t stream)
{
    const float* emb     = (const float*)d_in[0];
    const float* f_ij    = (const float*)d_in[1];
    const int*   idx_i   = (const int*)d_in[2];
    const int*   idx_j   = (const int*)d_in[3];
    const float* Wi      = (const float*)d_in[4];
    const float* bi      = (const float*)d_in[5];
    const float* Wj      = (const float*)d_in[6];
    const float* bj      = (const float*)d_in[7];
    const float* Wg      = (const float*)d_in[8];
    const float* Wv      = (const float*)d_in[9];
    const float* bv      = (const float*)d_in[10];
    const float* gate    = (const float*)d_in[11];
    const float* res_w1  = (const float*)d_in[12];
    const float* res_b1  = (const float*)d_in[13];
    const float* res_w2  = (const float*)d_in[14];
    const float* res_b2  = (const float*)d_in[15];
    const float* ores_w1 = (const float*)d_in[16];
    const float* ores_b1 = (const float*)d_in[17];
    const float* ores_w2 = (const float*)d_in[18];
    const float* ores_b2 = (const float*)d_in[19];
    const float* Wout    = (const float*)d_in[20];
    const float* bout    = (const float*)d_in[21];

    const int N = in_sizes[0] / FDIM;   // 50000
    const int P = in_sizes[2];          // 800000

    // workspace
    float* xi      = (float*)d_ws;                      // [N,128]
    float* xj      = xi + (size_t)N * FDIM;             // [N,128]
    short* wsw     = (short*)(xj + (size_t)N * FDIM);   // 11 * 16384 bf16
    int*   counts  = (int*)(wsw + 11 * 16384);          // [N]
    int*   offsets = counts + N;                        // [N+1]
    int*   cursor  = offsets + N + 1;                   // [N]
    int*   bucket  = cursor + N;                        // [P]
    int*   jperm   = bucket + P;                        // [P]
    int*   bsum    = jperm + P;                         // [<=32]
    float* pred    = (float*)d_out;                     // [N,2]
    float* updated = (float*)d_out + (size_t)N * 2;     // [N,128]

    const dim3 blk(256);
    const int ggrid = (N + 63) / 64;
    const int pgrid = (P + 255) / 256;
    const int nb    = (N + 2047) / 2048;

    // weight preconversion (bf16, transposed, swizzled)
    WP wp;
    wp.w[0] = Wi; wp.w[1] = Wj;
    wp.w[2] = res_w1; wp.w[3] = res_w1 + 16384; wp.w[4] = res_w1 + 32768;
    wp.w[5] = res_w2; wp.w[6] = res_w2 + 16384; wp.w[7] = res_w2 + 32768;
    wp.w[8] = Wv; wp.w[9] = ores_w1; wp.w[10] = ores_w2;
    wconv<<<dim3(32, 11), blk, 0, stream>>>(wp, wsw);

    // CSR build (int atomics only)
    hipMemsetAsync(counts, 0, (size_t)N * sizeof(int), stream);
    hist_counts<<<pgrid, blk, 0, stream>>>(idx_i, counts, P);
    block_sums<<<nb, blk, 0, stream>>>(counts, bsum, N);
    scan_within<<<nb, blk, 0, stream>>>(counts, bsum, offsets, cursor, N, P);
    fill_buckets<<<pgrid, blk, 0, stream>>>(idx_i, idx_j, cursor, bucket, jperm, P);

    // xi = act(act(emb@Wi+bi)); xj = act(act(emb@Wj+bj))
    fused_embed<<<ggrid, blk, 0, stream>>>(emb, wsw, bi, bj, xi, xj, N);

    // xi[i] += sum over pairs of (f_ij @ Wg) * xj[idx_j]
    pair_gather_mfma<<<(N + 3) / 4, blk, 0, stream>>>(f_ij, bucket, jperm, offsets,
                                                      Wg, xj, xi, N);

    // 3 residual blocks
    fused_res<<<ggrid, blk, 0, stream>>>(wsw, res_b1, res_b2, xi, N, 3);

    // updated + ores residual + prediction
    fused_tail<<<ggrid, blk, 0, stream>>>(xi, emb, wsw, bv, gate,
                                          ores_b1, ores_b2, Wout, bout,
                                          updated, pred, N);
}

// Round 7
// 294.926 us; speedup vs baseline: 2.7298x; 1.1017x over previous
//
#include <hip/hip_runtime.h>
#include <hip/hip_bf16.h>

#define FDIM 128

typedef __attribute__((ext_vector_type(8))) short bf16x8;
typedef __attribute__((ext_vector_type(4))) float f32x4;

__device__ __forceinline__ float sp(float x) {
    // softplus = max(x,0) + ln2*log2(1 + 2^(-|x|*log2e)) ; HW v_exp/v_log
    float t = __builtin_amdgcn_exp2f(-fabsf(x) * 1.44269504088896f);
    return fmaxf(x, 0.0f) + 0.69314718055994531f * __builtin_amdgcn_logf(1.0f + t);
}

__device__ __forceinline__ unsigned short bfb(float x) {
    // f32 -> bf16 round-to-nearest-even (inputs finite)
    unsigned int u = __float_as_uint(x);
    u += 0x7FFFu + ((u >> 16) & 1u);
    return (unsigned short)(u >> 16);
}

__device__ __forceinline__ float bf2f(unsigned short u) {
    return __uint_as_float(((unsigned int)u) << 16);
}

__device__ __forceinline__ bf16x8 pack8(float4 a, float4 b) {
    bf16x8 f;
    f[0]=(short)bfb(a.x); f[1]=(short)bfb(a.y); f[2]=(short)bfb(a.z); f[3]=(short)bfb(a.w);
    f[4]=(short)bfb(b.x); f[5]=(short)bfb(b.y); f[6]=(short)bfb(b.z); f[7]=(short)bfb(b.w);
    return f;
}

// copy one pre-converted, pre-swizzled 32KB bf16 weight image into LDS.
__device__ __forceinline__ void stage_wt(short* Wt, const short* __restrict__ src, int t) {
    const uint4* s4 = (const uint4*)src;
    uint4* d4 = (uint4*)Wt;
#pragma unroll
    for (int i = 0; i < 8; ++i) d4[t + 256 * i] = s4[t + 256 * i];
}

// 32 MFMA: full K=128, 8 n-tiles against swizzled Wt[n][k].
__device__ __forceinline__ void mfma_128(const short* Wt, const bf16x8* afr,
                                         int lane, f32x4* acc) {
#pragma unroll
    for (int ks = 0; ks < 4; ++ks)
#pragma unroll
        for (int n = 0; n < 8; ++n) {
            int nn = n * 16 + (lane & 15);
            int byte = nn * 256 + (ks * 32 + (lane >> 4) * 8) * 2;
            byte ^= (nn & 7) << 4;
            bf16x8 bfr = *(const bf16x8*)((const char*)Wt + byte);
            acc[n] = __builtin_amdgcn_mfma_f32_16x16x32_bf16(afr[ks], bfr, acc[n], 0, 0, 0);
        }
}

// ---------------------------------------------------------------------------
// wconv: convert 11 [128,128] f32 weights -> transposed/swizzled bf16 images.
struct WP { const float* w[11]; };

__global__ __launch_bounds__(256) void wconv(WP wp, short* __restrict__ dst) {
    const float* W = wp.w[blockIdx.y];
    char* out = (char*)(dst + (size_t)blockIdx.y * 16384);
    int e = blockIdx.x * 256 + threadIdx.x;        // e = kp*128 + n
    int n = e & 127, k = (e >> 7) * 2;
    float a = W[(size_t)k * FDIM + n];
    float b = W[(size_t)(k + 1) * FDIM + n];
    unsigned int pk = (unsigned int)bfb(a) | ((unsigned int)bfb(b) << 16);
    int byte = (n * 256 + k * 2) ^ ((n & 7) << 4);
    *(unsigned int*)(out + byte) = pk;
}

// wgconv: pack Wg [16,128] into its MFMA B-fragment image.
// frag for (col, kg): 8 bf16 = Wg[kg*8+e][col], stored at shorts[(col*2+kg)*8].
__global__ __launch_bounds__(256) void wgconv(const float* __restrict__ Wg,
                                              short* __restrict__ wgf) {
    int t = threadIdx.x;             // t = col*2 + kg
    int col = t >> 1, kg = t & 1;
    bf16x8 f;
#pragma unroll
    for (int e = 0; e < 8; ++e)
        f[e] = (short)bfb(Wg[(size_t)(kg * 8 + e) * FDIM + col]);
    *(bf16x8*)(wgf + (size_t)t * 8) = f;
}

// ---------------------------------------------------------------------------
// fused_embed: xi = act(act(emb@Wi+bi)) [f32], xjb = act(act(emb@Wj+bj)) [bf16]
__global__ __launch_bounds__(256) void fused_embed(
    const float* __restrict__ emb, const short* __restrict__ wsw,
    const float* __restrict__ bi, const float* __restrict__ bj,
    float* __restrict__ xi, unsigned short* __restrict__ xjb, int nrows)
{
    __shared__ __align__(16) short Wt[FDIM * FDIM];   // 32 KB
    const int t = threadIdx.x, lane = t & 63, wave = t >> 6;
    const int cl = lane & 15, rg = lane >> 4;
    const int rowA = blockIdx.x * 64 + wave * 16 + cl;
    const int kc   = rg * 8;
    const int rb   = blockIdx.x * 64 + wave * 16 + rg * 4;
    const bool rowok = rowA < nrows;

    bf16x8 afr[4];
#pragma unroll
    for (int ks = 0; ks < 4; ++ks) {
        float4 a = make_float4(0.f,0.f,0.f,0.f), b = make_float4(0.f,0.f,0.f,0.f);
        if (rowok) {
            const float* xp = emb + (size_t)rowA * FDIM + ks * 32 + kc;
            a = *(const float4*)xp; b = *(const float4*)(xp + 4);
        }
        afr[ks] = pack8(a, b);
    }

    stage_wt(Wt, wsw + 0 * 16384, t);    // Wi
    __syncthreads();
    f32x4 acc[8];
#pragma unroll
    for (int n = 0; n < 8; ++n) acc[n] = (f32x4){0.f,0.f,0.f,0.f};
    mfma_128(Wt, afr, lane, acc);
#pragma unroll
    for (int n = 0; n < 8; ++n) {
        int col = n * 16 + cl; float bc = bi[col];
#pragma unroll
        for (int i = 0; i < 4; ++i) {
            int gr = rb + i;
            if (gr < nrows) xi[(size_t)gr * FDIM + col] = sp(sp(acc[n][i] + bc));
        }
    }
    __syncthreads();                     // Wt reads done before restage
    stage_wt(Wt, wsw + 1 * 16384, t);    // Wj
    __syncthreads();
#pragma unroll
    for (int n = 0; n < 8; ++n) acc[n] = (f32x4){0.f,0.f,0.f,0.f};
    mfma_128(Wt, afr, lane, acc);
#pragma unroll
    for (int n = 0; n < 8; ++n) {
        int col = n * 16 + cl; float bc = bj[col];
#pragma unroll
        for (int i = 0; i < 4; ++i) {
            int gr = rb + i;
            if (gr < nrows) xjb[(size_t)gr * FDIM + col] = bfb(sp(sp(acc[n][i] + bc)));
        }
    }
}

// ---------------------------------------------------------------------------
// fused_res: 3 residual blocks in-place, x in C-frag registers.
__global__ __launch_bounds__(256) void fused_res(
    const short* __restrict__ wsw,       // slots 2..4 = W1, 5..7 = W2
    const float* __restrict__ B1a, const float* __restrict__ B2a,
    float* __restrict__ X, int nrows, int nstages)
{
    __shared__ __align__(16) short Wt[FDIM * FDIM];   // 32 KB
    __shared__ __align__(16) short XH[64 * FDIM];     // 16 KB
    const int t = threadIdx.x, lane = t & 63, wave = t >> 6;
    const int cl = lane & 15, rg = lane >> 4;
    const int kc = rg * 8;
    const int lrowA = wave * 16 + cl;
    const int lrb   = wave * 16 + rg * 4;
    const int rb    = blockIdx.x * 64 + lrb;

    float xr[8][4];
#pragma unroll
    for (int n = 0; n < 8; ++n)
#pragma unroll
        for (int i = 0; i < 4; ++i) {
            int gr = rb + i;
            xr[n][i] = (gr < nrows) ? X[(size_t)gr * FDIM + n * 16 + cl] : 0.f;
        }

    for (int s = 0; s < nstages; ++s) {
        const float* b1 = B1a + (size_t)s * FDIM;
        const float* b2 = B2a + (size_t)s * FDIM;

#pragma unroll
        for (int n = 0; n < 8; ++n)
#pragma unroll
            for (int i = 0; i < 4; ++i) {
                int lr = lrb + i, col = n * 16 + cl;
                int byte = (lr * 256 + col * 2) ^ ((lr & 7) << 4);
                *(short*)((char*)XH + byte) = (short)bfb(sp(xr[n][i]));
            }
        __syncthreads();                                   // bar 1

        bf16x8 afr[4];
#pragma unroll
        for (int ks = 0; ks < 4; ++ks) {
            int byte = (lrowA * 256 + (ks * 32 + kc) * 2) ^ ((lrowA & 7) << 4);
            afr[ks] = *(const bf16x8*)((const char*)XH + byte);
        }
        stage_wt(Wt, wsw + (size_t)(2 + s) * 16384, t);    // W1
        __syncthreads();                                   // bar 2

        f32x4 acc[8];
#pragma unroll
        for (int n = 0; n < 8; ++n) acc[n] = (f32x4){0.f,0.f,0.f,0.f};
        mfma_128(Wt, afr, lane, acc);
#pragma unroll
        for (int n = 0; n < 8; ++n) {
            float bc = b1[n * 16 + cl];
#pragma unroll
            for (int i = 0; i < 4; ++i) {
                int lr = lrb + i, col = n * 16 + cl;
                int byte = (lr * 256 + col * 2) ^ ((lr & 7) << 4);
                *(short*)((char*)XH + byte) = (short)bfb(sp(acc[n][i] + bc));
            }
        }
        __syncthreads();                                   // bar 3

#pragma unroll
        for (int ks = 0; ks < 4; ++ks) {
            int byte = (lrowA * 256 + (ks * 32 + kc) * 2) ^ ((lrowA & 7) << 4);
            afr[ks] = *(const bf16x8*)((const char*)XH + byte);
        }
        stage_wt(Wt, wsw + (size_t)(5 + s) * 16384, t);    // W2
        __syncthreads();                                   // bar 4

#pragma unroll
        for (int n = 0; n < 8; ++n) acc[n] = (f32x4){0.f,0.f,0.f,0.f};
        mfma_128(Wt, afr, lane, acc);
#pragma unroll
        for (int n = 0; n < 8; ++n) {
            float bc = b2[n * 16 + cl];
#pragma unroll
            for (int i = 0; i < 4; ++i) xr[n][i] += acc[n][i] + bc;
        }
        __syncthreads();                                   // bar 5
    }

#pragma unroll
    for (int n = 0; n < 8; ++n)
#pragma unroll
        for (int i = 0; i < 4; ++i) {
            int gr = rb + i;
            if (gr < nrows) X[(size_t)gr * FDIM + n * 16 + cl] = xr[n][i];
        }
}

// ---------------------------------------------------------------------------
// fused_tail: updated = gate*emb + act(xi)@Wv + bv ; ores residual ; out proj
__global__ __launch_bounds__(256) void fused_tail(
    const float* __restrict__ xi, const float* __restrict__ emb,
    const short* __restrict__ wsw,       // slot 8 = Wv, 9 = ow1, 10 = ow2
    const float* __restrict__ bv, const float* __restrict__ gate,
    const float* __restrict__ ob1, const float* __restrict__ ob2,
    const float* __restrict__ Wout, const float* __restrict__ bout,
    float* __restrict__ updated, float* __restrict__ pred, int nrows)
{
    __shared__ __align__(16) short Wt[FDIM * FDIM];
    __shared__ __align__(16) short XH[64 * FDIM];
    const int t = threadIdx.x, lane = t & 63, wave = t >> 6;
    const int cl = lane & 15, rg = lane >> 4;
    const int kc = rg * 8;
    const int rowA  = blockIdx.x * 64 + wave * 16 + cl;
    const int lrowA = wave * 16 + cl;
    const int lrb   = wave * 16 + rg * 4;
    const int rb    = blockIdx.x * 64 + lrb;
    const bool rowok = rowA < nrows;

    bf16x8 afr[4];
#pragma unroll
    for (int ks = 0; ks < 4; ++ks) {
        float4 a = make_float4(0.f,0.f,0.f,0.f), b = make_float4(0.f,0.f,0.f,0.f);
        if (rowok) {
            const float* xp = xi + (size_t)rowA * FDIM + ks * 32 + kc;
            a = *(const float4*)xp; b = *(const float4*)(xp + 4);
        }
        a.x=sp(a.x); a.y=sp(a.y); a.z=sp(a.z); a.w=sp(a.w);
        b.x=sp(b.x); b.y=sp(b.y); b.z=sp(b.z); b.w=sp(b.w);
        afr[ks] = pack8(a, b);
    }

    stage_wt(Wt, wsw + (size_t)8 * 16384, t);     // Wv
    __syncthreads();
    f32x4 acc[8];
#pragma unroll
    for (int n = 0; n < 8; ++n) acc[n] = (f32x4){0.f,0.f,0.f,0.f};
    mfma_128(Wt, afr, lane, acc);

    float ur[8][4];
#pragma unroll
    for (int n = 0; n < 8; ++n) {
        int col = n * 16 + cl;
        float bc = bv[col], gc = gate[col];
#pragma unroll
        for (int i = 0; i < 4; ++i) {
            int gr = rb + i;
            float ev = (gr < nrows) ? emb[(size_t)gr * FDIM + col] : 0.f;
            ur[n][i] = fmaf(gc, ev, acc[n][i] + bc);
            if (gr < nrows) updated[(size_t)gr * FDIM + col] = ur[n][i];
        }
    }

#pragma unroll
    for (int n = 0; n < 8; ++n)
#pragma unroll
        for (int i = 0; i < 4; ++i) {
            int lr = lrb + i, col = n * 16 + cl;
            int byte = (lr * 256 + col * 2) ^ ((lr & 7) << 4);
            *(short*)((char*)XH + byte) = (short)bfb(sp(ur[n][i]));
        }
    __syncthreads();
#pragma unroll
    for (int ks = 0; ks < 4; ++ks) {
        int byte = (lrowA * 256 + (ks * 32 + kc) * 2) ^ ((lrowA & 7) << 4);
        afr[ks] = *(const bf16x8*)((const char*)XH + byte);
    }
    stage_wt(Wt, wsw + (size_t)9 * 16384, t);     // ow1
    __syncthreads();
#pragma unroll
    for (int n = 0; n < 8; ++n) acc[n] = (f32x4){0.f,0.f,0.f,0.f};
    mfma_128(Wt, afr, lane, acc);
#pragma unroll
    for (int n = 0; n < 8; ++n) {
        float bc = ob1[n * 16 + cl];
#pragma unroll
        for (int i = 0; i < 4; ++i) {
            int lr = lrb + i, col = n * 16 + cl;
            int byte = (lr * 256 + col * 2) ^ ((lr & 7) << 4);
            *(short*)((char*)XH + byte) = (short)bfb(sp(acc[n][i] + bc));
        }
    }
    __syncthreads();
#pragma unroll
    for (int ks = 0; ks < 4; ++ks) {
        int byte = (lrowA * 256 + (ks * 32 + kc) * 2) ^ ((lrowA & 7) << 4);
        afr[ks] = *(const bf16x8*)((const char*)XH + byte);
    }
    stage_wt(Wt, wsw + (size_t)10 * 16384, t);    // ow2
    __syncthreads();
#pragma unroll
    for (int n = 0; n < 8; ++n) acc[n] = (f32x4){0.f,0.f,0.f,0.f};
    mfma_128(Wt, afr, lane, acc);

    float p0[4] = {0.f,0.f,0.f,0.f}, p1[4] = {0.f,0.f,0.f,0.f};
#pragma unroll
    for (int n = 0; n < 8; ++n) {
        int col = n * 16 + cl;
        float bc = ob2[col];
        float2 w = *(const float2*)(Wout + col * 2);
#pragma unroll
        for (int i = 0; i < 4; ++i) {
            float y = ur[n][i] + acc[n][i] + bc;
            p0[i] = fmaf(y, w.x, p0[i]);
            p1[i] = fmaf(y, w.y, p1[i]);
        }
    }
#pragma unroll
    for (int m = 1; m < 16; m <<= 1)
#pragma unroll
        for (int i = 0; i < 4; ++i) {
            p0[i] += __shfl_xor(p0[i], m, 64);
            p1[i] += __shfl_xor(p1[i], m, 64);
        }
    if (cl == 0) {
        float b0 = bout[0], b1v = bout[1];
#pragma unroll
        for (int i = 0; i < 4; ++i) {
            int gr = rb + i;
            if (gr < nrows) {
                pred[(size_t)gr * 2 + 0] = p0[i] + b0;
                pred[(size_t)gr * 2 + 1] = p1[i] + b1v;
            }
        }
    }
}

// ---- CSR build ------------------------------------------------------------

__global__ __launch_bounds__(256) void hist_counts(
    const int* __restrict__ idx_i, int* __restrict__ counts, int npairs)
{
    int p = blockIdx.x * 256 + threadIdx.x;
    if (p < npairs) atomicAdd(&counts[idx_i[p]], 1);
}

__global__ __launch_bounds__(256) void block_sums(
    const int* __restrict__ counts, int* __restrict__ bsum, int n)
{
    __shared__ int s[256];
    const int t = threadIdx.x;
    const int base = blockIdx.x * 2048;
    int sum = 0;
#pragma unroll
    for (int i = 0; i < 8; ++i) {
        int idx = base + t + 256 * i;
        sum += (idx < n) ? counts[idx] : 0;
    }
    s[t] = sum;
    __syncthreads();
    for (int o = 128; o > 0; o >>= 1) {
        if (t < o) s[t] += s[t + o];
        __syncthreads();
    }
    if (t == 0) bsum[blockIdx.x] = s[0];
}

__global__ __launch_bounds__(256) void scan_within(
    const int* __restrict__ counts, const int* __restrict__ bsum,
    int* __restrict__ offsets, int* __restrict__ cursor, int n, int npairs)
{
    __shared__ int ld[2048];
    __shared__ int ps[256];
    __shared__ int tile_base;
    const int t = threadIdx.x;
    const int base = blockIdx.x * 2048;
    if (t == 0) {
        int s = 0;
        for (int i = 0; i < (int)blockIdx.x; ++i) s += bsum[i];
        tile_base = s;
    }
#pragma unroll
    for (int i = 0; i < 8; ++i) {
        int idx = base + t + 256 * i;
        ld[t + 256 * i] = (idx < n) ? counts[idx] : 0;
    }
    __syncthreads();
    int loc[8]; int s = 0;
#pragma unroll
    for (int i = 0; i < 8; ++i) { loc[i] = s; s += ld[t * 8 + i]; }
    ps[t] = s;
    __syncthreads();
    for (int o = 1; o < 256; o <<= 1) {
        int add = (t >= o) ? ps[t - o] : 0;
        __syncthreads();
        ps[t] += add;
        __syncthreads();
    }
    int tbase = tile_base + ((t == 0) ? 0 : ps[t - 1]);
#pragma unroll
    for (int i = 0; i < 8; ++i) {
        int idx = base + t * 8 + i;
        if (idx < n) { int v = tbase + loc[i]; offsets[idx] = v; cursor[idx] = v; }
    }
    if (blockIdx.x == gridDim.x - 1 && t == 255) offsets[n] = npairs;
}

__global__ __launch_bounds__(256) void fill_buckets(
    const int* __restrict__ idx_i, const int* __restrict__ idx_j,
    int* __restrict__ cursor, int* __restrict__ bucket,
    int* __restrict__ jperm, int npairs)
{
    int p = blockIdx.x * 256 + threadIdx.x;
    if (p >= npairs) return;
    int pos = atomicAdd(&cursor[idx_i[p]], 1);
    bucket[pos] = p;
    jperm[pos]  = idx_j[p];
}

// ---------------------------------------------------------------------------
// pair_gather_mfma: one wave per atom, 16-pair batches, g = f@Wg via MFMA,
// xj gathered as bf16 (half traffic), Wg frags preloaded from packed image.
__global__ __launch_bounds__(256) void pair_gather_mfma(
    const float* __restrict__ f_ij, const int* __restrict__ bucket,
    const int* __restrict__ jperm, const int* __restrict__ offsets,
    const short* __restrict__ wgf, const unsigned short* __restrict__ xjb,
    float* __restrict__ xi, int natoms)
{
    const int lane = threadIdx.x & 63;
    const int wave = threadIdx.x >> 6;
    const int atom = blockIdx.x * 4 + wave;
    if (atom >= natoms) return;
    const int cl = lane & 15;
    const int kg = lane >> 4;

    // Wg B-frags from packed image: frag(col=16n+cl, kg) at shorts[(col*2+kg)*8]
    bf16x8 wg[8];
#pragma unroll
    for (int n = 0; n < 8; ++n) {
        bf16x8 f = (bf16x8){0,0,0,0,0,0,0,0};
        if (kg < 2)
            f = *(const bf16x8*)(wgf + (size_t)(((n * 16 + cl) * 2 + kg)) * 8);
        wg[n] = f;
    }

    const int beg = offsets[atom], end = offsets[atom + 1];
    float acc[8];
#pragma unroll
    for (int n = 0; n < 8; ++n) acc[n] = 0.f;

    for (int base = beg; base < end; base += 16) {
        int cnt = end - base; if (cnt > 16) cnt = 16;

        int pv = 0, jv = 0;
        if (lane < cnt) {
            pv = bucket[base + lane];
            jv = jperm[base + lane];
        }

        // j index of this lane-group's 4 pair slots
        int jr0 = __shfl(jv, (lane >> 4) * 4 + 0, 64);
        int jr1 = __shfl(jv, (lane >> 4) * 4 + 1, 64);
        int jr2 = __shfl(jv, (lane >> 4) * 4 + 2, 64);
        int jr3 = __shfl(jv, (lane >> 4) * 4 + 3, 64);

        const unsigned short* x0 = xjb + (size_t)jr0 * FDIM;
        const unsigned short* x1 = xjb + (size_t)jr1 * FDIM;
        const unsigned short* x2 = xjb + (size_t)jr2 * FDIM;
        const unsigned short* x3 = xjb + (size_t)jr3 * FDIM;

        // xj gathers (bf16): lane covers (pair slot i, col 16n+cl)
        float xvv[8][4];
#pragma unroll
        for (int n = 0; n < 8; ++n) {
            int col = n * 16 + cl;
            xvv[n][0] = bf2f(x0[col]);
            xvv[n][1] = bf2f(x1[col]);
            xvv[n][2] = bf2f(x2[col]);
            xvv[n][3] = bf2f(x3[col]);
        }

        // f A-frag: row = pair slot (lane&15), k = kg*8+e (zero-padded)
        int prow = __shfl(pv, cl, 64);
        bf16x8 fv = (bf16x8){0,0,0,0,0,0,0,0};
        if (kg < 2 && cl < cnt) {
            const float* fp = f_ij + (size_t)prow * 16 + kg * 8;
            float4 fa = *(const float4*)fp;
            float4 fb = *(const float4*)(fp + 4);
            fv = pack8(fa, fb);
        }

#pragma unroll
        for (int n = 0; n < 8; ++n) {
            f32x4 c = (f32x4){0.f, 0.f, 0.f, 0.f};
            c = __builtin_amdgcn_mfma_f32_16x16x32_bf16(fv, wg[n], c, 0, 0, 0);
            acc[n] = fmaf(c[0], xvv[n][0], acc[n]);
            acc[n] = fmaf(c[1], xvv[n][1], acc[n]);
            acc[n] = fmaf(c[2], xvv[n][2], acc[n]);
            acc[n] = fmaf(c[3], xvv[n][3], acc[n]);
        }
    }

#pragma unroll
    for (int n = 0; n < 8; ++n) {
        acc[n] += __shfl_xor(acc[n], 16, 64);
        acc[n] += __shfl_xor(acc[n], 32, 64);
    }
    if (lane < 16) {
#pragma unroll
        for (int n = 0; n < 8; ++n) {
            float* dst = xi + (size_t)atom * FDIM + n * 16 + lane;
            *dst += acc[n];
        }
    }
}

extern "C" void kernel_launch(void* const* d_in, const int* in_sizes, int n_in,
                              void* d_out, int out_size, void* d_ws, size_t ws_size,
                              hipStream_t stream)
{
    const float* emb     = (const float*)d_in[0];
    const float* f_ij    = (const float*)d_in[1];
    const int*   idx_i   = (const int*)d_in[2];
    const int*   idx_j   = (const int*)d_in[3];
    const float* Wi      = (const float*)d_in[4];
    const float* bi      = (const float*)d_in[5];
    const float* Wj      = (const float*)d_in[6];
    const float* bj      = (const float*)d_in[7];
    const float* Wg      = (const float*)d_in[8];
    const float* Wv      = (const float*)d_in[9];
    const float* bv      = (const float*)d_in[10];
    const float* gate    = (const float*)d_in[11];
    const float* res_w1  = (const float*)d_in[12];
    const float* res_b1  = (const float*)d_in[13];
    const float* res_w2  = (const float*)d_in[14];
    const float* res_b2  = (const float*)d_in[15];
    const float* ores_w1 = (const float*)d_in[16];
    const float* ores_b1 = (const float*)d_in[17];
    const float* ores_w2 = (const float*)d_in[18];
    const float* ores_b2 = (const float*)d_in[19];
    const float* Wout    = (const float*)d_in[20];
    const float* bout    = (const float*)d_in[21];

    const int N = in_sizes[0] / FDIM;   // 50000
    const int P = in_sizes[2];          // 800000

    // workspace
    float*          xi      = (float*)d_ws;                      // [N,128] f32
    unsigned short* xjb     = (unsigned short*)(xi + (size_t)N * FDIM);  // [N,128] bf16
    short*          wsw     = (short*)(xjb + (size_t)N * FDIM);  // 11 * 16384 bf16
    short*          wgf     = wsw + 11 * 16384;                  // 2048 bf16
    int*            counts  = (int*)(wgf + 2048);                // [N]
    int*            offsets = counts + N;                        // [N+1]
    int*            cursor  = offsets + N + 1;                   // [N]
    int*            bucket  = cursor + N;                        // [P]
    int*            jperm   = bucket + P;                        // [P]
    int*            bsum    = jperm + P;                         // [<=32]
    float*          pred    = (float*)d_out;                     // [N,2]
    float*          updated = (float*)d_out + (size_t)N * 2;     // [N,128]

    const dim3 blk(256);
    const int ggrid = (N + 63) / 64;
    const int pgrid = (P + 255) / 256;
    const int nb    = (N + 2047) / 2048;

    // weight preconversion
    WP wp;
    wp.w[0] = Wi; wp.w[1] = Wj;
    wp.w[2] = res_w1; wp.w[3] = res_w1 + 16384; wp.w[4] = res_w1 + 32768;
    wp.w[5] = res_w2; wp.w[6] = res_w2 + 16384; wp.w[7] = res_w2 + 32768;
    wp.w[8] = Wv; wp.w[9] = ores_w1; wp.w[10] = ores_w2;
    wconv<<<dim3(32, 11), blk, 0, stream>>>(wp, wsw);
    wgconv<<<1, blk, 0, stream>>>(Wg, wgf);

    // CSR build (int atomics only)
    hipMemsetAsync(counts, 0, (size_t)N * sizeof(int), stream);
    hist_counts<<<pgrid, blk, 0, stream>>>(idx_i, counts, P);
    block_sums<<<nb, blk, 0, stream>>>(counts, bsum, N);
    scan_within<<<nb, blk, 0, stream>>>(counts, bsum, offsets, cursor, N, P);
    fill_buckets<<<pgrid, blk, 0, stream>>>(idx_i, idx_j, cursor, bucket, jperm, P);

    // xi = act(act(emb@Wi+bi)); xjb = bf16(act(act(emb@Wj+bj)))
    fused_embed<<<ggrid, blk, 0, stream>>>(emb, wsw, bi, bj, xi, xjb, N);

    // xi[i] += sum over pairs of (f_ij @ Wg) * xj[idx_j]
    pair_gather_mfma<<<(N + 3) / 4, blk, 0, stream>>>(f_ij, bucket, jperm, offsets,
                                                      wgf, xjb, xi, N);

    // 3 residual blocks
    fused_res<<<ggrid, blk, 0, stream>>>(wsw, res_b1, res_b2, xi, N, 3);

    // updated + ores residual + prediction
    fused_tail<<<ggrid, blk, 0, stream>>>(xi, emb, wsw, bv, gate,
                                          ores_b1, ores_b2, Wout, bout,
                                          updated, pred, N);
}